// Round 1
// 1651.384 us; speedup vs baseline: 1.3305x; 1.3305x over previous
//
#include <hip/hip_runtime.h>

// int4-grouped-quant GEMM: C[M,N] = A[M,K](fp32) @ dequant(Wq[K/2,N] int4-packed)
//
// v2 strategy: split format conversion out of the GEMM hot loop.
//   prepass 1: A fp32 -> bf16 row-major           (d_ws, 64 MiB)
//   prepass 2: Wq int4 -> bf16 packed [K/8][N][8] (d_ws+64MiB, 86 MiB)  -- dequant done ONCE
//   main GEMM: 128x128 tile, BK=64, 4 waves, 16x16x32 bf16 MFMA,
//              staging via global_load_lds width=16 (no staging VALU, no ds_write conflicts)
// Fallback to v1 (fused dequant) kernel if workspace is too small.

constexpr int M = 8192;
constexpr int K = 4096;
constexpr int N = 11008;

constexpr int BM = 128;
constexpr int BN = 128;
constexpr int BK = 64;

typedef short v8s __attribute__((ext_vector_type(8)));
typedef float v4f __attribute__((ext_vector_type(4)));

// round-to-nearest-even fp32 -> bf16, packed pair into one u32
__device__ __forceinline__ unsigned pack_bf16(float lo, float hi) {
    unsigned a = __builtin_bit_cast(unsigned, lo);
    a += 0x7FFFu + ((a >> 16) & 1u);
    unsigned b = __builtin_bit_cast(unsigned, hi);
    b += 0x7FFFu + ((b >> 16) & 1u);
    return (a >> 16) | (b & 0xFFFF0000u);
}

// ---------------- prepass 1: A fp32 -> bf16 (row-major [M,K]) ----------------
__global__ __launch_bounds__(256) void convert_a(const float* __restrict__ A,
                                                 uint4* __restrict__ Abf)
{
    const size_t idx = (size_t)blockIdx.x * 256 + threadIdx.x;  // one uint4 = 8 bf16
    const float4* src = reinterpret_cast<const float4*>(A) + idx * 2;
    float4 f0 = src[0];
    float4 f1 = src[1];
    uint4 w;
    w.x = pack_bf16(f0.x, f0.y);
    w.y = pack_bf16(f0.z, f0.w);
    w.z = pack_bf16(f1.x, f1.y);
    w.w = pack_bf16(f1.z, f1.w);
    Abf[idx] = w;
}

// ------- prepass 2: dequant Wq -> bf16 packed [K/8][N][8] (chunk layout) -------
// element (k, n) lives at ((k>>3)*N + n)*8 + (k&7); k order = (low,high) nibble pairs
__global__ __launch_bounds__(256) void dequant_w(const int* __restrict__ Wq,
                                                 const float* __restrict__ scale,
                                                 const int* __restrict__ zp,
                                                 uint4* __restrict__ Bp)
{
    const int n  = blockIdx.x * 256 + threadIdx.x;  // 0..N-1 (N = 43*256)
    const int kc = blockIdx.y;                      // k-chunk, 0..K/8-1
    const int g  = kc >> 4;                         // quant group (GS=128 -> 16 chunks/group)
    const float sc = scale[(size_t)g * N + n];
    const float zs = -sc * (float)zp[(size_t)g * N + n];
    const int* src = Wq + (size_t)(kc * 4) * N + n;
    unsigned q0 = (unsigned)src[0];
    unsigned q1 = (unsigned)src[(size_t)N];
    unsigned q2 = (unsigned)src[(size_t)2 * N];
    unsigned q3 = (unsigned)src[(size_t)3 * N];
    uint4 o;
    o.x = pack_bf16(fmaf((float)(q0 & 15u), sc, zs),
                    fmaf((float)((q0 >> 4) & 15u), sc, zs));
    o.y = pack_bf16(fmaf((float)(q1 & 15u), sc, zs),
                    fmaf((float)((q1 >> 4) & 15u), sc, zs));
    o.z = pack_bf16(fmaf((float)(q2 & 15u), sc, zs),
                    fmaf((float)((q2 >> 4) & 15u), sc, zs));
    o.w = pack_bf16(fmaf((float)(q3 & 15u), sc, zs),
                    fmaf((float)((q3 >> 4) & 15u), sc, zs));
    Bp[(size_t)kc * N + n] = o;
}

// ---------------- main GEMM: bf16 MFMA, global_load_lds staging ----------------
__global__ __launch_bounds__(256) void qgemm_bf16(
    const unsigned short* __restrict__ Abf,  // [M,K] bf16
    const unsigned short* __restrict__ Bp,   // [K/8][N][8] bf16
    float* __restrict__ C)
{
    // LDS: [k-chunk (8 wide)][row][8] -> every fragment read is ds_read_b128
    __shared__ unsigned short sA[(BK / 8) * BM * 8];   // 16 KiB
    __shared__ unsigned short sB[(BK / 8) * BN * 8];   // 16 KiB

    const int t  = threadIdx.x;
    const int m0 = blockIdx.x * BM;
    const int n0 = blockIdx.y * BN;

    const int lane = t & 63;
    const int wave = t >> 6;
    const int wm   = (wave & 1) * 64;
    const int wn   = (wave >> 1) * 64;
    const int l16  = lane & 15;
    const int quad = lane >> 4;

    v4f acc[4][4];
    #pragma unroll
    for (int i = 0; i < 4; ++i)
        #pragma unroll
        for (int j = 0; j < 4; ++j)
            acc[i][j] = (v4f){0.f, 0.f, 0.f, 0.f};

    for (int kt = 0; kt < K / BK; ++kt) {
        const int k0 = kt * BK;

        __syncthreads();  // previous tile fully consumed before overwrite

        // stage A and B: each a 16 KiB tile, 4 issues x 256 threads x 16 B.
        // slot s = i*256 + t; chunk c = s>>7; row r = s&127.
        // LDS dest is linear (slot*16) -> wave-uniform base + lane*16, conflict-free.
        #pragma unroll
        for (int i = 0; i < 4; ++i) {
            const int s = i * 256 + t;
            const int c = s >> 7;
            const int r = s & 127;
            const unsigned short* ga = Abf + (size_t)(m0 + r) * K + k0 + c * 8;
            const unsigned short* gb =
                Bp + ((size_t)((k0 >> 3) + c) * N + (n0 + r)) * 8;
            unsigned short* la = sA + (size_t)(s & ~63) * 8;
            unsigned short* lb = sB + (size_t)(s & ~63) * 8;
            __builtin_amdgcn_global_load_lds(
                (const __attribute__((address_space(1))) void*)ga,
                (__attribute__((address_space(3))) void*)la, 16, 0, 0);
            __builtin_amdgcn_global_load_lds(
                (const __attribute__((address_space(1))) void*)gb,
                (__attribute__((address_space(3))) void*)lb, 16, 0, 0);
        }

        asm volatile("s_waitcnt vmcnt(0)" ::: "memory");
        __syncthreads();

        // compute: 2 k-windows of 32, 16 MFMAs each per wave
        #pragma unroll
        for (int kw = 0; kw < 2; ++kw) {
            const int cb = kw * 4 + quad;
            v8s af[4], bfr[4];
            #pragma unroll
            for (int i = 0; i < 4; ++i)
                af[i] = *reinterpret_cast<const v8s*>(
                    &sA[(cb * BM + wm + i * 16 + l16) * 8]);
            #pragma unroll
            for (int j = 0; j < 4; ++j)
                bfr[j] = *reinterpret_cast<const v8s*>(
                    &sB[(cb * BN + wn + j * 16 + l16) * 8]);
            #pragma unroll
            for (int i = 0; i < 4; ++i)
                #pragma unroll
                for (int j = 0; j < 4; ++j)
                    acc[i][j] = __builtin_amdgcn_mfma_f32_16x16x32_bf16(
                        af[i], bfr[j], acc[i][j], 0, 0, 0);
        }
    }

    // epilogue: C/D layout col=lane&15, row=quad*4+reg
    #pragma unroll
    for (int i = 0; i < 4; ++i) {
        int rbase = m0 + wm + i * 16 + quad * 4;
        #pragma unroll
        for (int j = 0; j < 4; ++j) {
            int col = n0 + wn + j * 16 + l16;
            #pragma unroll
            for (int r = 0; r < 4; ++r)
                C[(size_t)(rbase + r) * N + col] = acc[i][j][r];
        }
    }
}

// ---------------- fallback v1 kernel (fused dequant) ----------------
__global__ __launch_bounds__(256) void qgemm_kernel(
    const float* __restrict__ A,
    const int*   __restrict__ Wq,
    const float* __restrict__ scale,
    const int*   __restrict__ zp,
    float*       __restrict__ C)
{
    __shared__ unsigned short sA[(BK / 8) * BM * 8];
    __shared__ unsigned short sB[(BK / 8) * BN * 8];

    const int t  = threadIdx.x;
    const int m0 = blockIdx.x * BM;
    const int n0 = blockIdx.y * BN;

    const int lane = t & 63;
    const int wave = t >> 6;
    const int wm   = (wave & 1) * 64;
    const int wn   = (wave >> 1) * 64;
    const int l16  = lane & 15;
    const int quad = lane >> 4;

    const int bn  = t & 127;
    const int brg = t >> 7;

    v4f acc[4][4];
    #pragma unroll
    for (int i = 0; i < 4; ++i)
        #pragma unroll
        for (int j = 0; j < 4; ++j)
            acc[i][j] = (v4f){0.f, 0.f, 0.f, 0.f};

    for (int kt = 0; kt < K / BK; ++kt) {
        const int k0 = kt * BK;
        const int gq = k0 >> 7;
        const float sc = scale[gq * N + n0 + bn];
        const float zs = -sc * (float)zp[gq * N + n0 + bn];

        __syncthreads();

        #pragma unroll
        for (int p = 0; p < 4; ++p) {
            int idx = t + p * 256;
            int m = idx >> 3;
            int c = idx & 7;
            const float* src = A + (size_t)(m0 + m) * K + k0 + c * 8;
            float4 f0 = *reinterpret_cast<const float4*>(src);
            float4 f1 = *reinterpret_cast<const float4*>(src + 4);
            uint4 w;
            w.x = pack_bf16(f0.x, f0.y);
            w.y = pack_bf16(f0.z, f0.w);
            w.z = pack_bf16(f1.x, f1.y);
            w.w = pack_bf16(f1.z, f1.w);
            *reinterpret_cast<uint4*>(&sA[(c * BM + m) * 8]) = w;
        }

        #pragma unroll
        for (int p = 0; p < 4; ++p) {
            int g = brg + p * 2;
            const int* src = Wq + (size_t)((k0 >> 1) + g * 4) * N + n0 + bn;
            unsigned q0 = (unsigned)src[0];
            unsigned q1 = (unsigned)src[N];
            unsigned q2 = (unsigned)src[2 * N];
            unsigned q3 = (unsigned)src[3 * N];
            uint4 o;
            o.x = pack_bf16(fmaf((float)(q0 & 15u), sc, zs),
                            fmaf((float)((q0 >> 4) & 15u), sc, zs));
            o.y = pack_bf16(fmaf((float)(q1 & 15u), sc, zs),
                            fmaf((float)((q1 >> 4) & 15u), sc, zs));
            o.z = pack_bf16(fmaf((float)(q2 & 15u), sc, zs),
                            fmaf((float)((q2 >> 4) & 15u), sc, zs));
            o.w = pack_bf16(fmaf((float)(q3 & 15u), sc, zs),
                            fmaf((float)((q3 >> 4) & 15u), sc, zs));
            *reinterpret_cast<uint4*>(&sB[(g * BN + bn) * 8]) = o;
        }

        __syncthreads();

        #pragma unroll
        for (int kw = 0; kw < 2; ++kw) {
            int cb = kw * 4 + quad;
            v8s af[4], bfr[4];
            #pragma unroll
            for (int i = 0; i < 4; ++i)
                af[i] = *reinterpret_cast<const v8s*>(&sA[(cb * BM + wm + i * 16 + l16) * 8]);
            #pragma unroll
            for (int j = 0; j < 4; ++j)
                bfr[j] = *reinterpret_cast<const v8s*>(&sB[(cb * BN + wn + j * 16 + l16) * 8]);
            #pragma unroll
            for (int i = 0; i < 4; ++i)
                #pragma unroll
                for (int j = 0; j < 4; ++j)
                    acc[i][j] = __builtin_amdgcn_mfma_f32_16x16x32_bf16(
                        af[i], bfr[j], acc[i][j], 0, 0, 0);
        }
    }

    #pragma unroll
    for (int i = 0; i < 4; ++i) {
        int rbase = m0 + wm + i * 16 + quad * 4;
        #pragma unroll
        for (int j = 0; j < 4; ++j) {
            int col = n0 + wn + j * 16 + l16;
            #pragma unroll
            for (int r = 0; r < 4; ++r)
                C[(size_t)(rbase + r) * N + col] = acc[i][j][r];
        }
    }
}

extern "C" void kernel_launch(void* const* d_in, const int* in_sizes, int n_in,
                              void* d_out, int out_size, void* d_ws, size_t ws_size,
                              hipStream_t stream) {
    const float* A     = (const float*)d_in[0];
    const int*   Wq    = (const int*)d_in[1];
    const float* scale = (const float*)d_in[2];
    const int*   zp    = (const int*)d_in[3];
    float*       C     = (float*)d_out;

    const size_t needA = (size_t)M * K * 2;            // 67,108,864 B
    const size_t needB = (size_t)(K / 8) * N * 16;     // 90,177,536 B

    if (d_ws != nullptr && ws_size >= needA + needB) {
        unsigned short* Abf = (unsigned short*)d_ws;
        unsigned short* Bp  = (unsigned short*)((char*)d_ws + needA);

        // prepass 1: M*K/8 uint4 units / 256 threads = 16384 blocks
        convert_a<<<dim3((unsigned)((size_t)M * K / 8 / 256)), dim3(256), 0, stream>>>(
            A, (uint4*)Abf);
        // prepass 2: grid (N/256, K/8) = (43, 512)
        dequant_w<<<dim3(N / 256, K / 8), dim3(256), 0, stream>>>(
            Wq, scale, zp, (uint4*)Bp);
        // main GEMM
        qgemm_bf16<<<dim3(M / BM, N / BN), dim3(256), 0, stream>>>(Abf, Bp, C);
    } else {
        qgemm_kernel<<<dim3(M / BM, N / BN), dim3(256), 0, stream>>>(A, Wq, scale, zp, C);
    }
}

// Round 2
// 1268.320 us; speedup vs baseline: 1.7323x; 1.3020x over previous
//
#include <hip/hip_runtime.h>

// int4-grouped-quant GEMM: C[M,N] = A[M,K](fp32) @ dequant(Wq[K/2,N] int4-packed)
//
// v3 strategy: prepasses write operands PRE-TILED as the exact LDS image:
//   A_t[mtile][kt][c][r][8]  (mtile=M/128, kt=K/64, c=8 k-chunks, r=128 rows)  64 MiB
//   B_t[ntile][kt][c][r][8]  (ntile=N/128, r=128 n-cols)                       86 MiB
// GEMM staging is then a contiguous 16 KiB copy per tile per operand:
// every global_load_lds wave-read is 64 consecutive 16B lanes (perfect
// coalescing), LDS dest linear, fragment ds_read_b128 pattern unchanged.
// Fallback to fused-dequant kernel if workspace too small.

constexpr int M = 8192;
constexpr int K = 4096;
constexpr int N = 11008;

constexpr int BM = 128;
constexpr int BN = 128;
constexpr int BK = 64;

typedef short v8s __attribute__((ext_vector_type(8)));
typedef float v4f __attribute__((ext_vector_type(4)));

// round-to-nearest-even fp32 -> bf16, packed pair into one u32
__device__ __forceinline__ unsigned pack_bf16(float lo, float hi) {
    unsigned a = __builtin_bit_cast(unsigned, lo);
    a += 0x7FFFu + ((a >> 16) & 1u);
    unsigned b = __builtin_bit_cast(unsigned, hi);
    b += 0x7FFFu + ((b >> 16) & 1u);
    return (a >> 16) | (b & 0xFFFF0000u);
}

// ---------------- prepass 1: A fp32 -> bf16 tiled [mtile][kt][c][r][8] ----------------
// unit u (16 B = 8 bf16): r=u&127, c=(u>>7)&7, kt=(u>>10)&63, mtile=u>>16
// covers A[mtile*128+r][kt*64+c*8 .. +7]
__global__ __launch_bounds__(256) void tile_a(const float* __restrict__ A,
                                              uint4* __restrict__ At)
{
    const size_t u = (size_t)blockIdx.x * 256 + threadIdx.x;
    const int r  = (int)(u & 127);
    const int c  = (int)((u >> 7) & 7);
    const int kt = (int)((u >> 10) & 63);
    const int mt = (int)(u >> 16);
    const float* src = A + (size_t)(mt * 128 + r) * K + kt * 64 + c * 8;
    float4 f0 = *reinterpret_cast<const float4*>(src);
    float4 f1 = *reinterpret_cast<const float4*>(src + 4);
    uint4 w;
    w.x = pack_bf16(f0.x, f0.y);
    w.y = pack_bf16(f0.z, f0.w);
    w.z = pack_bf16(f1.x, f1.y);
    w.w = pack_bf16(f1.z, f1.w);
    At[u] = w;  // contiguous writes across threads
}

// ------- prepass 2: dequant Wq -> bf16 tiled [ntile][kt][c][r][8] -------
// unit u: r=u&127, c=(u>>7)&7, kt=(u>>10)&63, ntile=u>>16; n = ntile*128+r
// covers W[kt*64+c*8 .. +7][n]; packed rows pr = kt*32+c*4 .. +3 (low nibble = even k)
__global__ __launch_bounds__(256) void tile_b(const int* __restrict__ Wq,
                                              const float* __restrict__ scale,
                                              const int* __restrict__ zp,
                                              uint4* __restrict__ Bt)
{
    const size_t u = (size_t)blockIdx.x * 256 + threadIdx.x;
    const int r  = (int)(u & 127);
    const int c  = (int)((u >> 7) & 7);
    const int kt = (int)((u >> 10) & 63);
    const int nt = (int)(u >> 16);
    const int n  = nt * 128 + r;
    const int g  = kt >> 1;  // quant group (GS=128 = 2 k-tiles)
    const float sc = scale[(size_t)g * N + n];
    const float zs = -sc * (float)zp[(size_t)g * N + n];
    const int* src = Wq + (size_t)(kt * 32 + c * 4) * N + n;
    unsigned q0 = (unsigned)src[0];
    unsigned q1 = (unsigned)src[(size_t)N];
    unsigned q2 = (unsigned)src[(size_t)2 * N];
    unsigned q3 = (unsigned)src[(size_t)3 * N];
    uint4 o;
    o.x = pack_bf16(fmaf((float)(q0 & 15u), sc, zs),
                    fmaf((float)((q0 >> 4) & 15u), sc, zs));
    o.y = pack_bf16(fmaf((float)(q1 & 15u), sc, zs),
                    fmaf((float)((q1 >> 4) & 15u), sc, zs));
    o.z = pack_bf16(fmaf((float)(q2 & 15u), sc, zs),
                    fmaf((float)((q2 >> 4) & 15u), sc, zs));
    o.w = pack_bf16(fmaf((float)(q3 & 15u), sc, zs),
                    fmaf((float)((q3 >> 4) & 15u), sc, zs));
    Bt[u] = o;
}

// ---------------- main GEMM: bf16 MFMA, contiguous global_load_lds staging ----------------
__global__ __launch_bounds__(256) void qgemm_bf16(
    const unsigned short* __restrict__ At,  // tiled, 16B unit index (mtile*64+kt)*1024 + c*128+r
    const unsigned short* __restrict__ Bt,  // tiled, 16B unit index (ntile*64+kt)*1024 + c*128+r
    float* __restrict__ C)
{
    // LDS: [k-chunk (8 wide)][row][8] -> every fragment read is ds_read_b128
    __shared__ unsigned short sA[(BK / 8) * BM * 8];   // 16 KiB
    __shared__ unsigned short sB[(BK / 8) * BN * 8];   // 16 KiB

    const int t = threadIdx.x;

    const int lane = t & 63;
    const int wave = t >> 6;
    const int wm   = (wave & 1) * 64;
    const int wn   = (wave >> 1) * 64;
    const int l16  = lane & 15;
    const int quad = lane >> 4;

    v4f acc[4][4];
    #pragma unroll
    for (int i = 0; i < 4; ++i)
        #pragma unroll
        for (int j = 0; j < 4; ++j)
            acc[i][j] = (v4f){0.f, 0.f, 0.f, 0.f};

    for (int kt = 0; kt < K / BK; ++kt) {
        // tile base in ushort units (16B unit * 8)
        const unsigned short* aTile = At + ((size_t)(blockIdx.x * 64 + kt) * 1024) * 8;
        const unsigned short* bTile = Bt + ((size_t)(blockIdx.y * 64 + kt) * 1024) * 8;

        __syncthreads();  // previous tile fully consumed before overwrite

        // stage A and B: contiguous 16 KiB each; 4 issues x 256 threads x 16 B.
        // wave reads 64 consecutive 16B lanes; LDS dest = wave-uniform base + lane*16.
        #pragma unroll
        for (int i = 0; i < 4; ++i) {
            const int s = i * 256 + t;
            const unsigned short* ga = aTile + (size_t)s * 8;
            const unsigned short* gb = bTile + (size_t)s * 8;
            unsigned short* la = sA + (size_t)(s & ~63) * 8;
            unsigned short* lb = sB + (size_t)(s & ~63) * 8;
            __builtin_amdgcn_global_load_lds(
                (const __attribute__((address_space(1))) void*)ga,
                (__attribute__((address_space(3))) void*)la, 16, 0, 0);
            __builtin_amdgcn_global_load_lds(
                (const __attribute__((address_space(1))) void*)gb,
                (__attribute__((address_space(3))) void*)lb, 16, 0, 0);
        }

        asm volatile("s_waitcnt vmcnt(0)" ::: "memory");
        __syncthreads();

        // compute: 2 k-windows of 32, 16 MFMAs each per wave
        #pragma unroll
        for (int kw = 0; kw < 2; ++kw) {
            const int cb = kw * 4 + quad;
            v8s af[4], bfr[4];
            #pragma unroll
            for (int i = 0; i < 4; ++i)
                af[i] = *reinterpret_cast<const v8s*>(
                    &sA[(cb * BM + wm + i * 16 + l16) * 8]);
            #pragma unroll
            for (int j = 0; j < 4; ++j)
                bfr[j] = *reinterpret_cast<const v8s*>(
                    &sB[(cb * BN + wn + j * 16 + l16) * 8]);
            #pragma unroll
            for (int i = 0; i < 4; ++i)
                #pragma unroll
                for (int j = 0; j < 4; ++j)
                    acc[i][j] = __builtin_amdgcn_mfma_f32_16x16x32_bf16(
                        af[i], bfr[j], acc[i][j], 0, 0, 0);
        }
    }

    // epilogue: C/D layout col=lane&15, row=quad*4+reg
    const int m0 = blockIdx.x * BM;
    const int n0 = blockIdx.y * BN;
    #pragma unroll
    for (int i = 0; i < 4; ++i) {
        int rbase = m0 + wm + i * 16 + quad * 4;
        #pragma unroll
        for (int j = 0; j < 4; ++j) {
            int col = n0 + wn + j * 16 + l16;
            #pragma unroll
            for (int r = 0; r < 4; ++r)
                C[(size_t)(rbase + r) * N + col] = acc[i][j][r];
        }
    }
}

// ---------------- fallback: fused dequant (v1) ----------------
__global__ __launch_bounds__(256) void qgemm_kernel(
    const float* __restrict__ A,
    const int*   __restrict__ Wq,
    const float* __restrict__ scale,
    const int*   __restrict__ zp,
    float*       __restrict__ C)
{
    __shared__ unsigned short sA[(BK / 8) * BM * 8];
    __shared__ unsigned short sB[(BK / 8) * BN * 8];

    const int t  = threadIdx.x;
    const int m0 = blockIdx.x * BM;
    const int n0 = blockIdx.y * BN;

    const int lane = t & 63;
    const int wave = t >> 6;
    const int wm   = (wave & 1) * 64;
    const int wn   = (wave >> 1) * 64;
    const int l16  = lane & 15;
    const int quad = lane >> 4;

    const int bn  = t & 127;
    const int brg = t >> 7;

    v4f acc[4][4];
    #pragma unroll
    for (int i = 0; i < 4; ++i)
        #pragma unroll
        for (int j = 0; j < 4; ++j)
            acc[i][j] = (v4f){0.f, 0.f, 0.f, 0.f};

    for (int kt = 0; kt < K / BK; ++kt) {
        const int k0 = kt * BK;
        const int gq = k0 >> 7;
        const float sc = scale[gq * N + n0 + bn];
        const float zs = -sc * (float)zp[gq * N + n0 + bn];

        __syncthreads();

        #pragma unroll
        for (int p = 0; p < 4; ++p) {
            int idx = t + p * 256;
            int m = idx >> 3;
            int c = idx & 7;
            const float* src = A + (size_t)(m0 + m) * K + k0 + c * 8;
            float4 f0 = *reinterpret_cast<const float4*>(src);
            float4 f1 = *reinterpret_cast<const float4*>(src + 4);
            uint4 w;
            w.x = pack_bf16(f0.x, f0.y);
            w.y = pack_bf16(f0.z, f0.w);
            w.z = pack_bf16(f1.x, f1.y);
            w.w = pack_bf16(f1.z, f1.w);
            *reinterpret_cast<uint4*>(&sA[(c * BM + m) * 8]) = w;
        }

        #pragma unroll
        for (int p = 0; p < 4; ++p) {
            int g = brg + p * 2;
            const int* src = Wq + (size_t)((k0 >> 1) + g * 4) * N + n0 + bn;
            unsigned q0 = (unsigned)src[0];
            unsigned q1 = (unsigned)src[N];
            unsigned q2 = (unsigned)src[2 * N];
            unsigned q3 = (unsigned)src[3 * N];
            uint4 o;
            o.x = pack_bf16(fmaf((float)(q0 & 15u), sc, zs),
                            fmaf((float)((q0 >> 4) & 15u), sc, zs));
            o.y = pack_bf16(fmaf((float)(q1 & 15u), sc, zs),
                            fmaf((float)((q1 >> 4) & 15u), sc, zs));
            o.z = pack_bf16(fmaf((float)(q2 & 15u), sc, zs),
                            fmaf((float)((q2 >> 4) & 15u), sc, zs));
            o.w = pack_bf16(fmaf((float)(q3 & 15u), sc, zs),
                            fmaf((float)((q3 >> 4) & 15u), sc, zs));
            *reinterpret_cast<uint4*>(&sB[(g * BN + bn) * 8]) = o;
        }

        __syncthreads();

        #pragma unroll
        for (int kw = 0; kw < 2; ++kw) {
            int cb = kw * 4 + quad;
            v8s af[4], bfr[4];
            #pragma unroll
            for (int i = 0; i < 4; ++i)
                af[i] = *reinterpret_cast<const v8s*>(&sA[(cb * BM + wm + i * 16 + l16) * 8]);
            #pragma unroll
            for (int j = 0; j < 4; ++j)
                bfr[j] = *reinterpret_cast<const v8s*>(&sB[(cb * BN + wn + j * 16 + l16) * 8]);
            #pragma unroll
            for (int i = 0; i < 4; ++i)
                #pragma unroll
                for (int j = 0; j < 4; ++j)
                    acc[i][j] = __builtin_amdgcn_mfma_f32_16x16x32_bf16(
                        af[i], bfr[j], acc[i][j], 0, 0, 0);
        }
    }

    #pragma unroll
    for (int i = 0; i < 4; ++i) {
        int rbase = m0 + wm + i * 16 + quad * 4;
        #pragma unroll
        for (int j = 0; j < 4; ++j) {
            int col = n0 + wn + j * 16 + l16;
            #pragma unroll
            for (int r = 0; r < 4; ++r)
                C[(size_t)(rbase + r) * N + col] = acc[i][j][r];
        }
    }
}

extern "C" void kernel_launch(void* const* d_in, const int* in_sizes, int n_in,
                              void* d_out, int out_size, void* d_ws, size_t ws_size,
                              hipStream_t stream) {
    const float* A     = (const float*)d_in[0];
    const int*   Wq    = (const int*)d_in[1];
    const float* scale = (const float*)d_in[2];
    const int*   zp    = (const int*)d_in[3];
    float*       C     = (float*)d_out;

    const size_t needA = (size_t)M * K * 2;                       // 67,108,864 B
    const size_t needB = (size_t)(N / 128) * (K / 64) * 1024 * 16; // 90,177,536 B

    if (d_ws != nullptr && ws_size >= needA + needB) {
        unsigned short* At = (unsigned short*)d_ws;
        unsigned short* Bt = (unsigned short*)((char*)d_ws + needA);

        // prepass 1: M*K/8 units / 256 = 16384 blocks
        tile_a<<<dim3((unsigned)((size_t)M * K / 8 / 256)), dim3(256), 0, stream>>>(
            A, (uint4*)At);
        // prepass 2: (N/128)*(K/64)*1024 units / 256 = 22016 blocks
        tile_b<<<dim3((unsigned)((size_t)(N / 128) * (K / 64) * 1024 / 256)), dim3(256), 0,
                 stream>>>(Wq, scale, zp, (uint4*)Bt);
        // main GEMM
        qgemm_bf16<<<dim3(M / BM, N / BN), dim3(256), 0, stream>>>(At, Bt, C);
    } else {
        qgemm_kernel<<<dim3(M / BM, N / BN), dim3(256), 0, stream>>>(A, Wq, scale, zp, C);
    }
}

// Round 3
// 1147.733 us; speedup vs baseline: 1.9143x; 1.1051x over previous
//
#include <hip/hip_runtime.h>

// int4-grouped-quant GEMM: C[M,N] = A[M,K](fp32) @ dequant(Wq[K/2,N] int4-packed)
//
// v4: 256x256 tile, BK=32, 8 waves, 4-buffer LDS rotation (128 KiB), counted
// vmcnt(8) pipeline (never drains to 0 in steady state), raw s_barrier (one per
// K-step), setprio around MFMA cluster. Operands pre-tiled by prepass into the
// exact LDS image [tile][kt][c][r][8], so staging is contiguous global_load_lds
// and all ds_read_b128 fragment reads are bank-conflict-free (measured 0).
// Fallback to fused-dequant kernel if workspace too small.

constexpr int M = 8192;
constexpr int K = 4096;
constexpr int N = 11008;

constexpr int BM = 256;
constexpr int BN = 256;
constexpr int BK = 32;
constexpr int KT = K / BK;  // 128 K-steps

typedef short v8s __attribute__((ext_vector_type(8)));
typedef float v4f __attribute__((ext_vector_type(4)));

// round-to-nearest-even fp32 -> bf16, packed pair into one u32
__device__ __forceinline__ unsigned pack_bf16(float lo, float hi) {
    unsigned a = __builtin_bit_cast(unsigned, lo);
    a += 0x7FFFu + ((a >> 16) & 1u);
    unsigned b = __builtin_bit_cast(unsigned, hi);
    b += 0x7FFFu + ((b >> 16) & 1u);
    return (a >> 16) | (b & 0xFFFF0000u);
}

// ---------------- fused prepass ----------------
// Part A (blocks [0, 4096)): A fp32 -> bf16 tiled At[mt][kt][c][r][8]
//   thread = one (mt, kt, r): reads 128 B contiguous (full lines), writes 4
//   units; consecutive lanes -> consecutive r -> writes coalesce to 1 KiB runs.
// Part B (blocks [4096, 26112)): dequant Wq -> bf16 tiled Bt[nt][kt][c][r][8]
//   thread = one unit (nt,kt,c,r); lanes -> consecutive n: reads coalesce to
//   256 B per packed row, writes to contiguous 16 B units.
constexpr int PREP_A_BLOCKS = (M / 256) * KT * 256 / 256;          // 4096
constexpr int PREP_B_BLOCKS = (N / 256) * KT * 4 * 256 / 256;      // 22016

__global__ __launch_bounds__(256) void prep(const float* __restrict__ A,
                                            const int* __restrict__ Wq,
                                            const float* __restrict__ scale,
                                            const int* __restrict__ zp,
                                            uint4* __restrict__ At,
                                            uint4* __restrict__ Bt)
{
    const int tid = threadIdx.x;
    if (blockIdx.x < PREP_A_BLOCKS) {
        const int u  = blockIdx.x * 256 + tid;   // (mt,kt,r)
        const int r  = u & 255;
        const int kt = (u >> 8) & 127;
        const int mt = u >> 15;
        const float* src = A + (size_t)(mt * 256 + r) * K + kt * 32;
        float4 f[8];
        #pragma unroll
        for (int i = 0; i < 8; ++i)
            f[i] = reinterpret_cast<const float4*>(src)[i];
        const size_t base = (size_t)(mt * KT + kt) * 1024 + r;
        #pragma unroll
        for (int c = 0; c < 4; ++c) {
            uint4 w;
            w.x = pack_bf16(f[2 * c].x, f[2 * c].y);
            w.y = pack_bf16(f[2 * c].z, f[2 * c].w);
            w.z = pack_bf16(f[2 * c + 1].x, f[2 * c + 1].y);
            w.w = pack_bf16(f[2 * c + 1].z, f[2 * c + 1].w);
            At[base + c * 256] = w;
        }
    } else {
        const size_t u = (size_t)(blockIdx.x - PREP_A_BLOCKS) * 256 + tid;
        const int r  = (int)(u & 255);
        const int c  = (int)((u >> 8) & 3);
        const int kt = (int)((u >> 10) & 127);
        const int nt = (int)(u >> 17);
        const int n  = nt * 256 + r;
        const int g  = kt >> 2;  // quant group (GS=128 = 4 K-steps of 32)
        const float sc = scale[(size_t)g * N + n];
        const float zs = -sc * (float)zp[(size_t)g * N + n];
        const int* src = Wq + (size_t)(kt * 16 + c * 4) * N + n;
        unsigned q0 = (unsigned)src[0];
        unsigned q1 = (unsigned)src[(size_t)N];
        unsigned q2 = (unsigned)src[(size_t)2 * N];
        unsigned q3 = (unsigned)src[(size_t)3 * N];
        uint4 o;
        o.x = pack_bf16(fmaf((float)(q0 & 15u), sc, zs),
                        fmaf((float)((q0 >> 4) & 15u), sc, zs));
        o.y = pack_bf16(fmaf((float)(q1 & 15u), sc, zs),
                        fmaf((float)((q1 >> 4) & 15u), sc, zs));
        o.z = pack_bf16(fmaf((float)(q2 & 15u), sc, zs),
                        fmaf((float)((q2 >> 4) & 15u), sc, zs));
        o.w = pack_bf16(fmaf((float)(q3 & 15u), sc, zs),
                        fmaf((float)((q3 >> 4) & 15u), sc, zs));
        Bt[u] = o;
    }
}

// ---------------- main GEMM ----------------
// LDS: 4 buffers x (A: 1024 units + B: 1024 units) x 16 B = 128 KiB.
// Unit s within a tile: c = s>>8 (k-chunk of 8), r = s&255 (row/col).

__device__ __forceinline__ void stage_step(const unsigned short* __restrict__ At,
                                           const unsigned short* __restrict__ Bt,
                                           int bx, int by, int t, int buf,
                                           int tid, unsigned short* sMem)
{
    const unsigned short* aT = At + (size_t)(bx * KT + t) * 1024 * 8;
    const unsigned short* bT = Bt + (size_t)(by * KT + t) * 1024 * 8;
    unsigned short* sa = sMem + (size_t)buf * 2048 * 8;
    unsigned short* sb = sa + 1024 * 8;
    #pragma unroll
    for (int i = 0; i < 2; ++i) {
        const int s = i * 512 + tid;
        __builtin_amdgcn_global_load_lds(
            (const __attribute__((address_space(1))) void*)(aT + (size_t)s * 8),
            (__attribute__((address_space(3))) void*)(sa + (size_t)(s & ~63) * 8),
            16, 0, 0);
        __builtin_amdgcn_global_load_lds(
            (const __attribute__((address_space(1))) void*)(bT + (size_t)s * 8),
            (__attribute__((address_space(3))) void*)(sb + (size_t)(s & ~63) * 8),
            16, 0, 0);
    }
}

__device__ __forceinline__ void compute_step(const unsigned short* sMem, int buf,
                                             int wm, int wn, int quad, int l16,
                                             v4f (&acc)[8][4])
{
    const unsigned short* sa = sMem + (size_t)buf * 2048 * 8;
    const unsigned short* sb = sa + 1024 * 8;
    v8s af[8], bfr[4];
    #pragma unroll
    for (int i = 0; i < 8; ++i)
        af[i] = *reinterpret_cast<const v8s*>(&sa[(quad * 256 + wm + i * 16 + l16) * 8]);
    #pragma unroll
    for (int j = 0; j < 4; ++j)
        bfr[j] = *reinterpret_cast<const v8s*>(&sb[(quad * 256 + wn + j * 16 + l16) * 8]);
    __builtin_amdgcn_s_setprio(1);
    #pragma unroll
    for (int i = 0; i < 8; ++i)
        #pragma unroll
        for (int j = 0; j < 4; ++j)
            acc[i][j] = __builtin_amdgcn_mfma_f32_16x16x32_bf16(
                af[i], bfr[j], acc[i][j], 0, 0, 0);
    __builtin_amdgcn_s_setprio(0);
}

__global__ __launch_bounds__(512, 2) void qgemm_bf16(
    const unsigned short* __restrict__ At,
    const unsigned short* __restrict__ Bt,
    float* __restrict__ C)
{
    __shared__ unsigned short sMem[4 * 2048 * 8];  // 128 KiB

    const int tid  = threadIdx.x;
    const int bx   = blockIdx.x;
    const int by   = blockIdx.y;
    const int lane = tid & 63;
    const int wave = tid >> 6;
    const int wm   = (wave >> 2) * 128;  // 2 m-halves
    const int wn   = (wave & 3) * 64;    // 4 n-quarters
    const int l16  = lane & 15;
    const int quad = lane >> 4;

    v4f acc[8][4];
    #pragma unroll
    for (int i = 0; i < 8; ++i)
        #pragma unroll
        for (int j = 0; j < 4; ++j)
            acc[i][j] = (v4f){0.f, 0.f, 0.f, 0.f};

    // prologue: prefetch K-steps 0,1,2 into buffers 0,1,2 (12 loads/thread)
    stage_step(At, Bt, bx, by, 0, 0, tid, sMem);
    stage_step(At, Bt, bx, by, 1, 1, tid, sMem);
    stage_step(At, Bt, bx, by, 2, 2, tid, sMem);

    // main loop: one raw barrier + counted vmcnt per K-step; never drain to 0
    // until the tail. Invariants:
    //  - vmcnt(8)+barrier at iter t => step t's loads (all waves) have landed
    //    (exactly the 8 newest loads are steps t+1,t+2).
    //  - stage of step t+3 overwrites buf[(t-1)&3], consumed at iter t-1 and
    //    separated by this iteration's barrier.
    for (int t = 0; t < KT; ++t) {
        if (t < KT - 2) {
            asm volatile("s_waitcnt vmcnt(8)" ::: "memory");
        } else if (t == KT - 2) {
            asm volatile("s_waitcnt vmcnt(4)" ::: "memory");
        } else {
            asm volatile("s_waitcnt vmcnt(0)" ::: "memory");
        }
        __builtin_amdgcn_s_barrier();
        if (t + 3 < KT)
            stage_step(At, Bt, bx, by, t + 3, (t + 3) & 3, tid, sMem);
        compute_step(sMem, t & 3, wm, wn, quad, l16, acc);
    }

    // epilogue: C/D layout col=lane&15, row=quad*4+reg
    const int m0 = bx * BM;
    const int n0 = by * BN;
    #pragma unroll
    for (int i = 0; i < 8; ++i) {
        int rbase = m0 + wm + i * 16 + quad * 4;
        #pragma unroll
        for (int j = 0; j < 4; ++j) {
            int col = n0 + wn + j * 16 + l16;
            #pragma unroll
            for (int r = 0; r < 4; ++r)
                C[(size_t)(rbase + r) * N + col] = acc[i][j][r];
        }
    }
}

// ---------------- fallback: fused dequant (v1, no workspace) ----------------
constexpr int FBM = 128, FBN = 128, FBK = 64;

__global__ __launch_bounds__(256) void qgemm_kernel(
    const float* __restrict__ A,
    const int*   __restrict__ Wq,
    const float* __restrict__ scale,
    const int*   __restrict__ zp,
    float*       __restrict__ C)
{
    __shared__ unsigned short sA[(FBK / 8) * FBM * 8];
    __shared__ unsigned short sB[(FBK / 8) * FBN * 8];

    const int t  = threadIdx.x;
    const int m0 = blockIdx.x * FBM;
    const int n0 = blockIdx.y * FBN;

    const int lane = t & 63;
    const int wave = t >> 6;
    const int wm   = (wave & 1) * 64;
    const int wn   = (wave >> 1) * 64;
    const int l16  = lane & 15;
    const int quad = lane >> 4;

    const int bn  = t & 127;
    const int brg = t >> 7;

    v4f acc[4][4];
    #pragma unroll
    for (int i = 0; i < 4; ++i)
        #pragma unroll
        for (int j = 0; j < 4; ++j)
            acc[i][j] = (v4f){0.f, 0.f, 0.f, 0.f};

    for (int kt = 0; kt < K / FBK; ++kt) {
        const int k0 = kt * FBK;
        const int gq = k0 >> 7;
        const float sc = scale[gq * N + n0 + bn];
        const float zs = -sc * (float)zp[gq * N + n0 + bn];

        __syncthreads();

        #pragma unroll
        for (int p = 0; p < 4; ++p) {
            int idx = t + p * 256;
            int m = idx >> 3;
            int c = idx & 7;
            const float* src = A + (size_t)(m0 + m) * K + k0 + c * 8;
            float4 f0 = *reinterpret_cast<const float4*>(src);
            float4 f1 = *reinterpret_cast<const float4*>(src + 4);
            uint4 w;
            w.x = pack_bf16(f0.x, f0.y);
            w.y = pack_bf16(f0.z, f0.w);
            w.z = pack_bf16(f1.x, f1.y);
            w.w = pack_bf16(f1.z, f1.w);
            *reinterpret_cast<uint4*>(&sA[(c * FBM + m) * 8]) = w;
        }

        #pragma unroll
        for (int p = 0; p < 4; ++p) {
            int g = brg + p * 2;
            const int* src = Wq + (size_t)((k0 >> 1) + g * 4) * N + n0 + bn;
            unsigned q0 = (unsigned)src[0];
            unsigned q1 = (unsigned)src[N];
            unsigned q2 = (unsigned)src[2 * N];
            unsigned q3 = (unsigned)src[3 * N];
            uint4 o;
            o.x = pack_bf16(fmaf((float)(q0 & 15u), sc, zs),
                            fmaf((float)((q0 >> 4) & 15u), sc, zs));
            o.y = pack_bf16(fmaf((float)(q1 & 15u), sc, zs),
                            fmaf((float)((q1 >> 4) & 15u), sc, zs));
            o.z = pack_bf16(fmaf((float)(q2 & 15u), sc, zs),
                            fmaf((float)((q2 >> 4) & 15u), sc, zs));
            o.w = pack_bf16(fmaf((float)(q3 & 15u), sc, zs),
                            fmaf((float)((q3 >> 4) & 15u), sc, zs));
            *reinterpret_cast<uint4*>(&sB[(g * FBN + bn) * 8]) = o;
        }

        __syncthreads();

        #pragma unroll
        for (int kw = 0; kw < 2; ++kw) {
            int cb = kw * 4 + quad;
            v8s af[4], bfr[4];
            #pragma unroll
            for (int i = 0; i < 4; ++i)
                af[i] = *reinterpret_cast<const v8s*>(&sA[(cb * FBM + wm + i * 16 + l16) * 8]);
            #pragma unroll
            for (int j = 0; j < 4; ++j)
                bfr[j] = *reinterpret_cast<const v8s*>(&sB[(cb * FBN + wn + j * 16 + l16) * 8]);
            #pragma unroll
            for (int i = 0; i < 4; ++i)
                #pragma unroll
                for (int j = 0; j < 4; ++j)
                    acc[i][j] = __builtin_amdgcn_mfma_f32_16x16x32_bf16(
                        af[i], bfr[j], acc[i][j], 0, 0, 0);
        }
    }

    #pragma unroll
    for (int i = 0; i < 4; ++i) {
        int rbase = m0 + wm + i * 16 + quad * 4;
        #pragma unroll
        for (int j = 0; j < 4; ++j) {
            int col = n0 + wn + j * 16 + l16;
            #pragma unroll
            for (int r = 0; r < 4; ++r)
                C[(size_t)(rbase + r) * N + col] = acc[i][j][r];
        }
    }
}

extern "C" void kernel_launch(void* const* d_in, const int* in_sizes, int n_in,
                              void* d_out, int out_size, void* d_ws, size_t ws_size,
                              hipStream_t stream) {
    const float* A     = (const float*)d_in[0];
    const int*   Wq    = (const int*)d_in[1];
    const float* scale = (const float*)d_in[2];
    const int*   zp    = (const int*)d_in[3];
    float*       C     = (float*)d_out;

    const size_t needA = (size_t)M * K * 2;   // 67,108,864 B
    const size_t needB = (size_t)N * K * 2;   // 90,177,536 B

    if (d_ws != nullptr && ws_size >= needA + needB) {
        unsigned short* At = (unsigned short*)d_ws;
        unsigned short* Bt = (unsigned short*)((char*)d_ws + needA);

        prep<<<dim3(PREP_A_BLOCKS + PREP_B_BLOCKS), dim3(256), 0, stream>>>(
            A, Wq, scale, zp, (uint4*)At, (uint4*)Bt);
        qgemm_bf16<<<dim3(M / BM, N / BN), dim3(512), 0, stream>>>(At, Bt, C);
    } else {
        qgemm_kernel<<<dim3(M / FBM, N / FBN), dim3(256), 0, stream>>>(A, Wq, scale, zp, C);
    }
}

// Round 4
// 1103.191 us; speedup vs baseline: 1.9916x; 1.0404x over previous
//
#include <hip/hip_runtime.h>

// int4-grouped-quant GEMM: C[M,N] = A[M,K](fp32) @ dequant(Wq[K/2,N] int4-packed)
//
// v5: 8-phase schedule (m201 port). 256x256 tile, 8 waves (2M x 4N), 4-buffer
// LDS rotation (4 x 32 KiB = 128 KiB) = K-128 macro-iteration. Each macro is 8
// phases: {stage 16KiB quantum, [vmcnt(10) even phases], s_barrier, ds_read
// subtile (4 or 8 x b128), 16 MFMA under setprio(1), s_barrier}. Derived waits:
// steady-state outstanding = 14 gloads at each even-phase checkpoint, vmcnt(10)
// waits exactly the A,B quanta of the step being computed. Tail macro peeled
// with vmcnt 10/8/4/0. Operands pre-tiled by prepass into the exact LDS image
// [tile][kt][c][r][8] (conflict-free ds_read_b128, measured 0).
// Fallback to fused-dequant kernel if workspace too small.

constexpr int M = 8192;
constexpr int K = 4096;
constexpr int N = 11008;

constexpr int BM = 256;
constexpr int BN = 256;
constexpr int BK = 32;
constexpr int KT = K / BK;  // 128 K-steps, 32 macros of 4

typedef short v8s __attribute__((ext_vector_type(8)));
typedef float v4f __attribute__((ext_vector_type(4)));

#define BAR() asm volatile("s_barrier" ::: "memory")

// round-to-nearest-even fp32 -> bf16, packed pair into one u32
__device__ __forceinline__ unsigned pack_bf16(float lo, float hi) {
    unsigned a = __builtin_bit_cast(unsigned, lo);
    a += 0x7FFFu + ((a >> 16) & 1u);
    unsigned b = __builtin_bit_cast(unsigned, hi);
    b += 0x7FFFu + ((b >> 16) & 1u);
    return (a >> 16) | (b & 0xFFFF0000u);
}

// ---------------- fused prepass ----------------
constexpr int PREP_A_BLOCKS = (M / 256) * KT * 256 / 256;          // 4096
constexpr int PREP_B_BLOCKS = (N / 256) * KT * 4 * 256 / 256;      // 22016

__global__ __launch_bounds__(256) void prep(const float* __restrict__ A,
                                            const int* __restrict__ Wq,
                                            const float* __restrict__ scale,
                                            const int* __restrict__ zp,
                                            uint4* __restrict__ At,
                                            uint4* __restrict__ Bt)
{
    const int tid = threadIdx.x;
    if (blockIdx.x < PREP_A_BLOCKS) {
        const int u  = blockIdx.x * 256 + tid;   // (mt,kt,r)
        const int r  = u & 255;
        const int kt = (u >> 8) & 127;
        const int mt = u >> 15;
        const float* src = A + (size_t)(mt * 256 + r) * K + kt * 32;
        float4 f[8];
        #pragma unroll
        for (int i = 0; i < 8; ++i)
            f[i] = reinterpret_cast<const float4*>(src)[i];
        const size_t base = (size_t)(mt * KT + kt) * 1024 + r;
        #pragma unroll
        for (int c = 0; c < 4; ++c) {
            uint4 w;
            w.x = pack_bf16(f[2 * c].x, f[2 * c].y);
            w.y = pack_bf16(f[2 * c].z, f[2 * c].w);
            w.z = pack_bf16(f[2 * c + 1].x, f[2 * c + 1].y);
            w.w = pack_bf16(f[2 * c + 1].z, f[2 * c + 1].w);
            At[base + c * 256] = w;
        }
    } else {
        const size_t u = (size_t)(blockIdx.x - PREP_A_BLOCKS) * 256 + tid;
        const int r  = (int)(u & 255);
        const int c  = (int)((u >> 8) & 3);
        const int kt = (int)((u >> 10) & 127);
        const int nt = (int)(u >> 17);
        const int n  = nt * 256 + r;
        const int g  = kt >> 2;  // quant group (GS=128 = 4 K-steps of 32)
        const float sc = scale[(size_t)g * N + n];
        const float zs = -sc * (float)zp[(size_t)g * N + n];
        const int* src = Wq + (size_t)(kt * 16 + c * 4) * N + n;
        unsigned q0 = (unsigned)src[0];
        unsigned q1 = (unsigned)src[(size_t)N];
        unsigned q2 = (unsigned)src[(size_t)2 * N];
        unsigned q3 = (unsigned)src[(size_t)3 * N];
        uint4 o;
        o.x = pack_bf16(fmaf((float)(q0 & 15u), sc, zs),
                        fmaf((float)((q0 >> 4) & 15u), sc, zs));
        o.y = pack_bf16(fmaf((float)(q1 & 15u), sc, zs),
                        fmaf((float)((q1 >> 4) & 15u), sc, zs));
        o.z = pack_bf16(fmaf((float)(q2 & 15u), sc, zs),
                        fmaf((float)((q2 >> 4) & 15u), sc, zs));
        o.w = pack_bf16(fmaf((float)(q3 & 15u), sc, zs),
                        fmaf((float)((q3 >> 4) & 15u), sc, zs));
        Bt[u] = o;
    }
}

// ---------------- main GEMM ----------------
// LDS: 4 buffers x (A: 1024 units + B: 1024 units) x 16 B = 128 KiB.
// Stage quantum = one operand tile of one K-step (16 KiB, 2 gloads/thread).

__device__ __forceinline__ void stage_A(const unsigned short* __restrict__ At,
                                        int bx, int t, int buf, int tid,
                                        unsigned short* sMem)
{
    const unsigned short* aT = At + (size_t)(bx * KT + t) * 1024 * 8;
    unsigned short* sa = sMem + (size_t)buf * 2048 * 8;
    #pragma unroll
    for (int i = 0; i < 2; ++i) {
        const int s = i * 512 + tid;
        __builtin_amdgcn_global_load_lds(
            (const __attribute__((address_space(1))) void*)(aT + (size_t)s * 8),
            (__attribute__((address_space(3))) void*)(sa + (size_t)(s & ~63) * 8),
            16, 0, 0);
    }
}

__device__ __forceinline__ void stage_B(const unsigned short* __restrict__ Bt,
                                        int by, int t, int buf, int tid,
                                        unsigned short* sMem)
{
    const unsigned short* bT = Bt + (size_t)(by * KT + t) * 1024 * 8;
    unsigned short* sb = sMem + (size_t)buf * 2048 * 8 + 1024 * 8;
    #pragma unroll
    for (int i = 0; i < 2; ++i) {
        const int s = i * 512 + tid;
        __builtin_amdgcn_global_load_lds(
            (const __attribute__((address_space(1))) void*)(bT + (size_t)s * 8),
            (__attribute__((address_space(3))) void*)(sb + (size_t)(s & ~63) * 8),
            16, 0, 0);
    }
}

// one phase's MFMA cluster: i0=0 -> loads bfr[0..3]+af[0..3]; i0=4 -> af[4..7]
__device__ __forceinline__ void cluster(const unsigned short* sMem, int buf, int i0,
                                        int wm, int wn, int quad, int l16,
                                        v4f (&acc)[8][4], v8s (&bfr)[4])
{
    const unsigned short* sa = sMem + (size_t)buf * 2048 * 8;
    const unsigned short* sb = sa + 1024 * 8;
    v8s af[4];
    if (i0 == 0) {
        #pragma unroll
        for (int j = 0; j < 4; ++j)
            bfr[j] = *reinterpret_cast<const v8s*>(
                &sb[(quad * 256 + wn + j * 16 + l16) * 8]);
    }
    #pragma unroll
    for (int i = 0; i < 4; ++i)
        af[i] = *reinterpret_cast<const v8s*>(
            &sa[(quad * 256 + wm + (i0 + i) * 16 + l16) * 8]);
    __builtin_amdgcn_s_setprio(1);
    #pragma unroll
    for (int i = 0; i < 4; ++i)
        #pragma unroll
        for (int j = 0; j < 4; ++j)
            acc[i0 + i][j] = __builtin_amdgcn_mfma_f32_16x16x32_bf16(
                af[i], bfr[j], acc[i0 + i][j], 0, 0, 0);
    __builtin_amdgcn_s_setprio(0);
}

__global__ __launch_bounds__(512, 2) void qgemm_bf16(
    const unsigned short* __restrict__ At,
    const unsigned short* __restrict__ Bt,
    float* __restrict__ C)
{
    __shared__ unsigned short sMem[4 * 2048 * 8];  // 128 KiB

    const int tid  = threadIdx.x;
    const int bx   = blockIdx.x;
    const int by   = blockIdx.y;
    const int lane = tid & 63;
    const int wave = tid >> 6;
    const int wm   = (wave >> 2) * 128;  // 2 m-halves
    const int wn   = (wave & 3) * 64;    // 4 n-quarters
    const int l16  = lane & 15;
    const int quad = lane >> 4;

    v4f acc[8][4];
    #pragma unroll
    for (int i = 0; i < 8; ++i)
        #pragma unroll
        for (int j = 0; j < 4; ++j)
            acc[i][j] = (v4f){0.f, 0.f, 0.f, 0.f};

    // prologue: quanta A(0),B(0),A(1),B(1),A(2),B(2) -> 12 gloads outstanding
    stage_A(At, bx, 0, 0, tid, sMem);
    stage_B(Bt, by, 0, 0, tid, sMem);
    stage_A(At, bx, 1, 1, tid, sMem);
    stage_B(Bt, by, 1, 1, tid, sMem);
    stage_A(At, bx, 2, 2, tid, sMem);
    stage_B(Bt, by, 2, 2, tid, sMem);

    v8s bfr[4];

    // main macros: steps s0..s0+3 in buffers 0..3; 8 phases each.
    // Even-phase invariant: outstanding = 14 gloads after this phase's stage;
    // vmcnt(10) waits exactly the A,B quanta of the step computed this phase.
    for (int u = 0; u < KT / 4 - 1; ++u) {
        const int s0 = 4 * u;
        // p0: stage A(s0+3)->buf3 (freed prev macro p7); compute step s0 c0
        stage_A(At, bx, s0 + 3, 3, tid, sMem);
        asm volatile("s_waitcnt vmcnt(10)" ::: "memory");
        BAR();
        cluster(sMem, 0, 0, wm, wn, quad, l16, acc, bfr);
        BAR();
        // p1: stage B(s0+3)->buf3; compute step s0 c1
        stage_B(Bt, by, s0 + 3, 3, tid, sMem);
        BAR();
        cluster(sMem, 0, 4, wm, wn, quad, l16, acc, bfr);
        BAR();
        // p2: stage A(s0+4)->buf0 (freed after p1); compute step s0+1 c0
        stage_A(At, bx, s0 + 4, 0, tid, sMem);
        asm volatile("s_waitcnt vmcnt(10)" ::: "memory");
        BAR();
        cluster(sMem, 1, 0, wm, wn, quad, l16, acc, bfr);
        BAR();
        // p3
        stage_B(Bt, by, s0 + 4, 0, tid, sMem);
        BAR();
        cluster(sMem, 1, 4, wm, wn, quad, l16, acc, bfr);
        BAR();
        // p4
        stage_A(At, bx, s0 + 5, 1, tid, sMem);
        asm volatile("s_waitcnt vmcnt(10)" ::: "memory");
        BAR();
        cluster(sMem, 2, 0, wm, wn, quad, l16, acc, bfr);
        BAR();
        // p5
        stage_B(Bt, by, s0 + 5, 1, tid, sMem);
        BAR();
        cluster(sMem, 2, 4, wm, wn, quad, l16, acc, bfr);
        BAR();
        // p6
        stage_A(At, bx, s0 + 6, 2, tid, sMem);
        asm volatile("s_waitcnt vmcnt(10)" ::: "memory");
        BAR();
        cluster(sMem, 3, 0, wm, wn, quad, l16, acc, bfr);
        BAR();
        // p7
        stage_B(Bt, by, s0 + 6, 2, tid, sMem);
        BAR();
        cluster(sMem, 3, 4, wm, wn, quad, l16, acc, bfr);
        BAR();
    }

    // tail macro (steps KT-4..KT-1): stage only A,B(KT-1); drain vmcnt 10/8/4/0
    {
        stage_A(At, bx, KT - 1, 3, tid, sMem);
        asm volatile("s_waitcnt vmcnt(10)" ::: "memory");
        BAR();
        cluster(sMem, 0, 0, wm, wn, quad, l16, acc, bfr);
        BAR();
        stage_B(Bt, by, KT - 1, 3, tid, sMem);
        BAR();
        cluster(sMem, 0, 4, wm, wn, quad, l16, acc, bfr);
        BAR();
        asm volatile("s_waitcnt vmcnt(8)" ::: "memory");
        BAR();
        cluster(sMem, 1, 0, wm, wn, quad, l16, acc, bfr);
        BAR();
        cluster(sMem, 1, 4, wm, wn, quad, l16, acc, bfr);
        BAR();
        asm volatile("s_waitcnt vmcnt(4)" ::: "memory");
        BAR();
        cluster(sMem, 2, 0, wm, wn, quad, l16, acc, bfr);
        BAR();
        cluster(sMem, 2, 4, wm, wn, quad, l16, acc, bfr);
        BAR();
        asm volatile("s_waitcnt vmcnt(0)" ::: "memory");
        BAR();
        cluster(sMem, 3, 0, wm, wn, quad, l16, acc, bfr);
        BAR();
        cluster(sMem, 3, 4, wm, wn, quad, l16, acc, bfr);
    }

    // epilogue: C/D layout col=lane&15, row=quad*4+reg
    const int m0 = bx * BM;
    const int n0 = by * BN;
    #pragma unroll
    for (int i = 0; i < 8; ++i) {
        int rbase = m0 + wm + i * 16 + quad * 4;
        #pragma unroll
        for (int j = 0; j < 4; ++j) {
            int col = n0 + wn + j * 16 + l16;
            #pragma unroll
            for (int r = 0; r < 4; ++r)
                C[(size_t)(rbase + r) * N + col] = acc[i][j][r];
        }
    }
}

// ---------------- fallback: fused dequant (v1, no workspace) ----------------
constexpr int FBM = 128, FBN = 128, FBK = 64;

__global__ __launch_bounds__(256) void qgemm_kernel(
    const float* __restrict__ A,
    const int*   __restrict__ Wq,
    const float* __restrict__ scale,
    const int*   __restrict__ zp,
    float*       __restrict__ C)
{
    __shared__ unsigned short sA[(FBK / 8) * FBM * 8];
    __shared__ unsigned short sB[(FBK / 8) * FBN * 8];

    const int t  = threadIdx.x;
    const int m0 = blockIdx.x * FBM;
    const int n0 = blockIdx.y * FBN;

    const int lane = t & 63;
    const int wave = t >> 6;
    const int wm   = (wave & 1) * 64;
    const int wn   = (wave >> 1) * 64;
    const int l16  = lane & 15;
    const int quad = lane >> 4;

    const int bn  = t & 127;
    const int brg = t >> 7;

    v4f acc[4][4];
    #pragma unroll
    for (int i = 0; i < 4; ++i)
        #pragma unroll
        for (int j = 0; j < 4; ++j)
            acc[i][j] = (v4f){0.f, 0.f, 0.f, 0.f};

    for (int kt = 0; kt < K / FBK; ++kt) {
        const int k0 = kt * FBK;
        const int gq = k0 >> 7;
        const float sc = scale[gq * N + n0 + bn];
        const float zs = -sc * (float)zp[gq * N + n0 + bn];

        __syncthreads();

        #pragma unroll
        for (int p = 0; p < 4; ++p) {
            int idx = t + p * 256;
            int m = idx >> 3;
            int c = idx & 7;
            const float* src = A + (size_t)(m0 + m) * K + k0 + c * 8;
            float4 f0 = *reinterpret_cast<const float4*>(src);
            float4 f1 = *reinterpret_cast<const float4*>(src + 4);
            uint4 w;
            w.x = pack_bf16(f0.x, f0.y);
            w.y = pack_bf16(f0.z, f0.w);
            w.z = pack_bf16(f1.x, f1.y);
            w.w = pack_bf16(f1.z, f1.w);
            *reinterpret_cast<uint4*>(&sA[(c * FBM + m) * 8]) = w;
        }

        #pragma unroll
        for (int p = 0; p < 4; ++p) {
            int g = brg + p * 2;
            const int* src = Wq + (size_t)((k0 >> 1) + g * 4) * N + n0 + bn;
            unsigned q0 = (unsigned)src[0];
            unsigned q1 = (unsigned)src[N];
            unsigned q2 = (unsigned)src[2 * N];
            unsigned q3 = (unsigned)src[3 * N];
            uint4 o;
            o.x = pack_bf16(fmaf((float)(q0 & 15u), sc, zs),
                            fmaf((float)((q0 >> 4) & 15u), sc, zs));
            o.y = pack_bf16(fmaf((float)(q1 & 15u), sc, zs),
                            fmaf((float)((q1 >> 4) & 15u), sc, zs));
            o.z = pack_bf16(fmaf((float)(q2 & 15u), sc, zs),
                            fmaf((float)((q2 >> 4) & 15u), sc, zs));
            o.w = pack_bf16(fmaf((float)(q3 & 15u), sc, zs),
                            fmaf((float)((q3 >> 4) & 15u), sc, zs));
            *reinterpret_cast<uint4*>(&sB[(g * FBN + bn) * 8]) = o;
        }

        __syncthreads();

        #pragma unroll
        for (int kw = 0; kw < 2; ++kw) {
            int cb = kw * 4 + quad;
            v8s af[4], bfr[4];
            #pragma unroll
            for (int i = 0; i < 4; ++i)
                af[i] = *reinterpret_cast<const v8s*>(&sA[(cb * FBM + wm + i * 16 + l16) * 8]);
            #pragma unroll
            for (int j = 0; j < 4; ++j)
                bfr[j] = *reinterpret_cast<const v8s*>(&sB[(cb * FBN + wn + j * 16 + l16) * 8]);
            #pragma unroll
            for (int i = 0; i < 4; ++i)
                #pragma unroll
                for (int j = 0; j < 4; ++j)
                    acc[i][j] = __builtin_amdgcn_mfma_f32_16x16x32_bf16(
                        af[i], bfr[j], acc[i][j], 0, 0, 0);
        }
    }

    #pragma unroll
    for (int i = 0; i < 4; ++i) {
        int rbase = m0 + wm + i * 16 + quad * 4;
        #pragma unroll
        for (int j = 0; j < 4; ++j) {
            int col = n0 + wn + j * 16 + l16;
            #pragma unroll
            for (int r = 0; r < 4; ++r)
                C[(size_t)(rbase + r) * N + col] = acc[i][j][r];
        }
    }
}

extern "C" void kernel_launch(void* const* d_in, const int* in_sizes, int n_in,
                              void* d_out, int out_size, void* d_ws, size_t ws_size,
                              hipStream_t stream) {
    const float* A     = (const float*)d_in[0];
    const int*   Wq    = (const int*)d_in[1];
    const float* scale = (const float*)d_in[2];
    const int*   zp    = (const int*)d_in[3];
    float*       C     = (float*)d_out;

    const size_t needA = (size_t)M * K * 2;   // 67,108,864 B
    const size_t needB = (size_t)N * K * 2;   // 90,177,536 B

    if (d_ws != nullptr && ws_size >= needA + needB) {
        unsigned short* At = (unsigned short*)d_ws;
        unsigned short* Bt = (unsigned short*)((char*)d_ws + needA);

        prep<<<dim3(PREP_A_BLOCKS + PREP_B_BLOCKS), dim3(256), 0, stream>>>(
            A, Wq, scale, zp, (uint4*)At, (uint4*)Bt);
        qgemm_bf16<<<dim3(M / BM, N / BN), dim3(512), 0, stream>>>(At, Bt, C);
    } else {
        qgemm_kernel<<<dim3(M / FBM, N / FBN), dim3(256), 0, stream>>>(A, Wq, scale, zp, C);
    }
}